// Round 9
// baseline (196.781 us; speedup 1.0000x reference)
//
#include <hip/hip_runtime.h>

typedef unsigned short u16;
typedef unsigned int u32;
typedef __attribute__((ext_vector_type(8))) short short8;
typedef __attribute__((ext_vector_type(4))) float f32x4;

#define BB 8
#define CCH 256
#define HH 64
#define WW 64
#define HP 66
#define NPOS 4096
#define KTOT 2304

// ---- ws layout (bytes) ----
#define XT_BYTES   17842176ull                 // bf16 [8][66][66][256]
#define W2R_OFF    17842176ull                 // bf16 1.18MB: FRAGMENT layout [36gs][2j][4wr][4ao][64lane][8e]
#define WOFF2_OFF  19021824ull                 // bf16 [32][2304] (row-major, k_off2)
#define OFF2_OFF   40402944ull                 // float2 [8][9][4096]
#define WS_MIN     42762240ull

__device__ __forceinline__ u16 f2bf(float f) {
    union { float f; u32 u; } v; v.f = f;
    u32 r = v.u + 0x7FFFu + ((v.u >> 16) & 1u);
    return (u16)(r >> 16);
}
__device__ __forceinline__ u32 pk2(float a, float b) {
    return (u32)f2bf(a) | ((u32)f2bf(b) << 16);
}
// single-instruction packed f32->bf16 (RNE, same bits as pk2 for finite values)
__device__ __forceinline__ u32 cvtpk(float lo, float hi) {
    u32 r;
    asm("v_cvt_pk_bf16_f32 %0, %1, %2" : "=v"(r) : "v"(lo), "v"(hi));
    return r;
}
__device__ __forceinline__ void bf2x2(u32 p, float& a, float& b) {
    union { u32 u; float f; } va, vb;
    va.u = p << 16; vb.u = p & 0xffff0000u;
    a = va.f; b = vb.f;
}
// async global->LDS, 16B per lane; LDS dest = wave-uniform base + lane*16
__device__ __forceinline__ void ldg_lds16(const u16* g, u16* l) {
    __builtin_amdgcn_global_load_lds((const __attribute__((address_space(1))) u32*)g,
                                     (__attribute__((address_space(3))) u32*)l, 16, 0, 0);
}

// ---- K_PRE: weight-reorder (MFMA-fragment layout) + border-zero + transpose ----
__global__ __launch_bounds__(256) void k_pre(const float* __restrict__ w, const float* __restrict__ w_off,
                                             const float* __restrict__ x,
                                             u16* __restrict__ W2r, u16* __restrict__ Woff2,
                                             u16* __restrict__ xT) {
    __shared__ __align__(16) float SH[4608];   // prep uses 2304; transpose uses 64x72
    int bx = blockIdx.x;
    int t = threadIdx.x;
    if (bx < 256) {
        // emit W2r in MFMA-fragment order so k_gemm's A-loads are 1KB coalesced:
        // element (o=wr*64+ao*16+m, kcol=gs*64+(j*4+q)*8+e) at
        //   u16 idx = (((gs*2+j)*4+wr)*4+ao)*512 + (q*16+m)*8 + e
        int o = bx;
        const float* src = w + (size_t)o * 2304;
#pragma unroll
        for (int j = 0; j < 9; ++j) SH[j * 256 + t] = src[j * 256 + t];   // SH[ch*9+tap]
        __syncthreads();
        int m = o & 15, ao = (o >> 4) & 3, wr = o >> 6;
        for (int ci = t; ci < 288; ci += 256) {
            int gs = ci >> 3, jj = (ci >> 2) & 1, q = ci & 3;
            int kbase = gs * 64 + (jj * 4 + q) * 8;
            int tap = kbase >> 8, ch0 = kbase & 255;      // 8 contiguous ch, one tap
            uint4 sv;
            sv.x = pk2(SH[(ch0 + 0) * 9 + tap], SH[(ch0 + 1) * 9 + tap]);
            sv.y = pk2(SH[(ch0 + 2) * 9 + tap], SH[(ch0 + 3) * 9 + tap]);
            sv.z = pk2(SH[(ch0 + 4) * 9 + tap], SH[(ch0 + 5) * 9 + tap]);
            sv.w = pk2(SH[(ch0 + 6) * 9 + tap], SH[(ch0 + 7) * 9 + tap]);
            u16* dst = W2r + ((size_t)((((gs * 2 + jj) * 4 + wr) << 2) + ao) << 9)
                           + ((q * 16 + m) << 3);
            *(uint4*)dst = sv;
        }
    } else if (bx == 256) {
        for (int o2 = 0; o2 < 32; ++o2) {
            if (o2 < 18) {
                const float* src = w_off + (size_t)o2 * 2304;
#pragma unroll
                for (int j = 0; j < 9; ++j) SH[j * 256 + t] = src[j * 256 + t];
                __syncthreads();
#pragma unroll
                for (int k = 0; k < 9; ++k) Woff2[(size_t)o2 * 2304 + k * 256 + t] = f2bf(SH[t * 9 + k]);
                __syncthreads();
            } else {
#pragma unroll
                for (int k = 0; k < 9; ++k) Woff2[(size_t)o2 * 2304 + k * 256 + t] = 0;
            }
        }
    } else if (bx < 777) {
        // border zero: 2080 positions, 4 per block (64 lanes each)
        int idx = (bx - 257) * 4 + (t >> 6);
        int b = idx / 260, m = idx - b * 260;
        int y, xx;
        if (m < 66)       { y = 0;  xx = m; }
        else if (m < 132) { y = 65; xx = m - 66; }
        else if (m < 196) { y = m - 132 + 1; xx = 0; }
        else              { y = m - 196 + 1; xx = 65; }
        u16* p = xT + ((size_t)(b * HP + y) * HP + xx) * CCH + (t & 63) * 4;
        uint2 zz; zz.x = 0; zz.y = 0;
        *(uint2*)p = zz;
    } else {
        int idx = bx - 777;               // 2048 transpose tiles
        int b = idx & 7;                  // XCD pin
        int r = idx >> 3;
        int y = r & 63, c0 = (r >> 6) * 64;
        {
            int i = t >> 2, seg = t & 3;   // channel i, 16-float x-segment
            const float* src = x + (((size_t)(b * CCH + c0 + i) * HH + y) * WW) + seg * 16;
            float4 v0 = *(const float4*)(src);
            float4 v1 = *(const float4*)(src + 4);
            float4 v2 = *(const float4*)(src + 8);
            float4 v3 = *(const float4*)(src + 12);
            *(float4*)&SH[i * 72 + seg * 16]      = v0;
            *(float4*)&SH[i * 72 + seg * 16 + 4]  = v1;
            *(float4*)&SH[i * 72 + seg * 16 + 8]  = v2;
            *(float4*)&SH[i * 72 + seg * 16 + 12] = v3;
        }
        __syncthreads();
        {
            int xc = t >> 2, cs = t & 3;   // x-position xc, 16-channel segment cs
            u16* dst = xT + (((size_t)(b * HP + y + 1) * HP) + (xc + 1)) * CCH + c0 + cs * 16;
            u32 p[8];
#pragma unroll
            for (int j = 0; j < 8; ++j)
                p[j] = pk2(SH[(cs * 16 + 2 * j) * 72 + xc], SH[(cs * 16 + 2 * j + 1) * 72 + xc]);
            uint4 d0, d1;
            d0.x = p[0]; d0.y = p[1]; d0.z = p[2]; d0.w = p[3];
            d1.x = p[4]; d1.y = p[5]; d1.z = p[6]; d1.w = p[7];
            *(uint4*)dst = d0;
            *(uint4*)(dst + 8) = d1;
        }
    }
}

// ---- K_OFF2: offset conv, full K=2304 -> off2 directly (round-7 verified) ----
__global__ __launch_bounds__(256) void k_off2(const u16* __restrict__ xT,
                                              const u16* __restrict__ Woff2,
                                              const float* __restrict__ b_off,
                                              float2* __restrict__ off2) {
    __shared__ __align__(16) u16 AS[3][2048];   // [32 o-row][64 k] x3, 12KB
    __shared__ __align__(16) u16 BS[3][8192];   // [128 pos][64 k] x3, 48KB
    int b = blockIdx.x;
    int pos0 = blockIdx.y * 128;
    int t = threadIdx.x, lane = t & 63, wv = t >> 6;

    int srow = lane >> 3;
    int sw8 = ((lane & 7) ^ srow) << 3;
    const u16* pXb = xT + (size_t)b * HP * HP * CCH;

    f32x4 acc[2][2];
    f32x4 z = {0.f, 0.f, 0.f, 0.f};
    acc[0][0] = z; acc[0][1] = z; acc[1][0] = z; acc[1][1] = z;

    auto stage = [&](int gs, int d) {            // gs in [0,36): tap = gs>>2, cs = gs&3
        int t9 = gs >> 2, cs = gs & 3;
        int ky = t9 / 3, kx = t9 - (t9 / 3) * 3;
        int koff = t9 * 256 + cs * 64;           // A k-offset (Woff2 row-major [32][2304])
        {
            int row = wv * 8 + srow;
            ldg_lds16(Woff2 + (size_t)row * KTOT + koff + sw8, &AS[d][wv * 512]);
        }
#pragma unroll
        for (int i = 0; i < 4; ++i) {
            int inst = wv * 4 + i;
            int rowg = pos0 + inst * 8 + srow;
            int py_ = rowg >> 6, px_ = rowg & 63;
            const u16* g = pXb + (((size_t)(py_ + ky) * HP) + px_ + kx) * CCH + cs * 64 + sw8;
            ldg_lds16(g, &BS[d][inst * 512]);
        }
    };

    stage(0, 0);                                 // 5 loads
    stage(1, 1);                                 // 5 loads

    int m = lane & 15, q = lane >> 4, key = lane & 7;
    for (int gs = 0; gs < 36; ++gs) {
        int cur = gs % 3;
        if (gs <= 34) { asm volatile("s_waitcnt vmcnt(5)" ::: "memory"); }
        else          { asm volatile("s_waitcnt vmcnt(0)" ::: "memory"); }
        __builtin_amdgcn_s_barrier();            // stage(gs) visible; buf (gs+2)%3 free
        if (gs < 34) stage(gs + 2, (gs + 2) % 3);
#pragma unroll
        for (int j = 0; j < 2; ++j) {
            int slot8 = (((j * 4 + q) ^ key) << 3);
            short8 a0 = *(const short8*)&AS[cur][m * 64 + slot8];
            short8 a1 = *(const short8*)&AS[cur][(16 + m) * 64 + slot8];
            short8 b0 = *(const short8*)&BS[cur][(wv * 32 + m) * 64 + slot8];
            short8 b1 = *(const short8*)&BS[cur][(wv * 32 + 16 + m) * 64 + slot8];
            acc[0][0] = __builtin_amdgcn_mfma_f32_16x16x32_bf16(a0, b0, acc[0][0], 0, 0, 0);
            acc[0][1] = __builtin_amdgcn_mfma_f32_16x16x32_bf16(a0, b1, acc[0][1], 0, 0, 0);
            acc[1][0] = __builtin_amdgcn_mfma_f32_16x16x32_bf16(a1, b0, acc[1][0], 0, 0, 0);
            acc[1][1] = __builtin_amdgcn_mfma_f32_16x16x32_bf16(a1, b1, acc[1][1], 0, 0, 0);
        }
        asm volatile("s_waitcnt lgkmcnt(0)" ::: "memory");
    }

    int nn = lane & 15;
#pragma unroll
    for (int ao = 0; ao < 2; ++ao)
#pragma unroll
        for (int bn = 0; bn < 2; ++bn) {
            int pos = pos0 + wv * 32 + bn * 16 + nn;
#pragma unroll
            for (int rp = 0; rp < 2; ++rp) {
                int o = ao * 16 + q * 4 + rp * 2;
                if (o < 18) {
                    float2 v;
                    v.x = acc[ao][bn][rp * 2]     + b_off[o];
                    v.y = acc[ao][bn][rp * 2 + 1] + b_off[o + 1];
                    off2[(((size_t)(b * 9 + (o >> 1))) << 12) + pos] = v;
                }
            }
        }
}

// ---- K4: BM=256, BN=64; A-fragments DIRECT FROM GLOBAL (L2-hot, fragment-ordered 1KB
// coalesced loads) -> no A LDS -> LDS = BSF only (33.8KB) -> 2 blocks/CU, 4 waves/SIMD.
// Region/blend schedule byte-identical to verified round-4; all vmcnt compiler-managed:
// issue order per step [A(8) | blend(uses G(gs-1)) | gathers G(gs)(4) | MFMA(uses A)]
// pinned by sched_barrier -> blend waits vmcnt keeping A in flight, MFMA waits keeping G.
__global__ __launch_bounds__(512, 4) void k_gemm(const u16* __restrict__ xT,
                                                 const float2* __restrict__ off2,
                                                 const u16* __restrict__ W2rf,
                                                 const float* __restrict__ bias,
                                                 float* __restrict__ out) {
    __shared__ __align__(16) u16 BSF[64 * 264];  // [64 pos][256 k + 8 pad], 33.8KB
    int b = blockIdx.x;                          // linear%8==b -> XCD-pinned, xT slice L2-hot
    int pos0 = blockIdx.z * 64;
    int t = threadIdx.x, lane = t & 63, wv = t >> 6;   // wv 0..7
    int wr = wv >> 1, wc = wv & 1;               // 4M x 2N; per-wave 64x32 out

    int brow = t >> 3;                           // 0..63: blend pos-row
    int bcl = (t & 7) << 3;                      // 8-ch slot (u16 units)
    int bbase = b * HP * HP;

    f32x4 acc[4][2];
    f32x4 z = {0.f, 0.f, 0.f, 0.f};
#pragma unroll
    for (int i = 0; i < 4; ++i) { acc[i][0] = z; acc[i][1] = z; }

    // pipeline state (per thread: 1 pos-row, 8 channels per region)
    const u16* gp[4];
    float wt[4];
    float2 fnext;
    uint4 gv[4];

    auto computeState = [&](int tap) {
        int pos = pos0 + brow;
        int y = pos >> 6, x = pos & 63;
        int ky = tap / 3, kx = tap - (tap / 3) * 3;
        float pyf = (float)(y - 1 + ky) + fnext.x;
        float pxf = (float)(x - 1 + kx) + fnext.y;
        float y0f = floorf(pyf), x0f = floorf(pxf);
        int y0 = (int)y0f, x0 = (int)x0f;
        int y1 = y0 + 1, x1 = x0 + 1;
        float wy1 = pyf - y0f, wy0 = 1.f - wy1;
        float wx1 = pxf - x0f, wx0 = 1.f - wx1;
        bool vy0 = (y0 >= 0) & (y0 < HH), vy1 = (y1 >= 0) & (y1 < HH);
        bool vx0 = (x0 >= 0) & (x0 < WW), vx1 = (x1 >= 0) & (x1 < WW);
        int yc0 = min(max(y0, 0), HH - 1), yc1 = min(max(y1, 0), HH - 1);
        int xc0 = min(max(x0, 0), WW - 1), xc1 = min(max(x1, 0), WW - 1);
        wt[0] = (vy0 & vx0) ? wy0 * wx0 : 0.f;
        wt[1] = (vy0 & vx1) ? wy0 * wx1 : 0.f;
        wt[2] = (vy1 & vx0) ? wy1 * wx0 : 0.f;
        wt[3] = (vy1 & vx1) ? wy1 * wx1 : 0.f;
        gp[0] = xT + (size_t)(bbase + (yc0 + 1) * HP + xc0 + 1) * CCH + bcl;
        gp[1] = xT + (size_t)(bbase + (yc0 + 1) * HP + xc1 + 1) * CCH + bcl;
        gp[2] = xT + (size_t)(bbase + (yc1 + 1) * HP + xc0 + 1) * CCH + bcl;
        gp[3] = xT + (size_t)(bbase + (yc1 + 1) * HP + xc1 + 1) * CCH + bcl;
    };
    auto gatherRegion = [&](int rr) {            // 4 x 16B loads, region rr channels
#pragma unroll
        for (int c = 0; c < 4; ++c)
            gv[c] = *(const uint4*)(gp[c] + rr * 64);
    };
    auto blendWrite = [&](int rr) {              // blend gv -> BSF region rr
        float v[8];
#pragma unroll
        for (int dw = 0; dw < 4; ++dw) {
            float a0, b0_, a1, b1_, a2, b2_, a3, b3_;
            bf2x2(((const u32*)&gv[0])[dw], a0, b0_);
            bf2x2(((const u32*)&gv[1])[dw], a1, b1_);
            bf2x2(((const u32*)&gv[2])[dw], a2, b2_);
            bf2x2(((const u32*)&gv[3])[dw], a3, b3_);
            v[2 * dw]     = wt[0] * a0 + wt[1] * a1 + wt[2] * a2 + wt[3] * a3;
            v[2 * dw + 1] = wt[0] * b0_ + wt[1] * b1_ + wt[2] * b2_ + wt[3] * b3_;
        }
        uint4 sv;
        sv.x = cvtpk(v[0], v[1]); sv.y = cvtpk(v[2], v[3]);
        sv.z = cvtpk(v[4], v[5]); sv.w = cvtpk(v[6], v[7]);
        *(uint4*)&BSF[brow * 264 + rr * 64 + bcl] = sv;
    };

    // ---- prologue: fill all 4 regions of tap 0 (sync); prefetch off2(tap1) ----
    {
        fnext = off2[((size_t)(b * 9) << 12) + pos0 + brow];
        computeState(0);
#pragma unroll
        for (int rr = 0; rr < 4; ++rr) {
            gatherRegion(rr);
            blendWrite(rr);
        }
        fnext = off2[((size_t)(b * 9 + 1) << 12) + pos0 + brow];
        asm volatile("s_waitcnt lgkmcnt(0)" ::: "memory");   // BSF(tap0) ds_writes flushed
    }

    int m = lane & 15, q = lane >> 4;
    for (int gs = 0; gs <= 35; ++gs) {
        int t9 = gs >> 2, cs = gs & 3;
        __builtin_amdgcn_s_barrier();            // BSF region cs ready; region (cs+3)&3 free

        // A-fragments for step gs: 8 coalesced 1KB loads from fragment-ordered W2rf (L2-hot)
        short8 af[8];
#pragma unroll
        for (int jj = 0; jj < 2; ++jj)
#pragma unroll
            for (int ao = 0; ao < 4; ++ao)
                af[jj * 4 + ao] = *(const short8*)(W2rf
                    + ((size_t)((((gs * 2 + jj) * 4 + wr) << 2) + ao) << 9) + (lane << 3));
        __builtin_amdgcn_sched_barrier(0);       // FIFO: A issued before gathers

        // blend last step's gathers -> region (cs+3)&3 (gv-use waits vmcnt -> A stays in flight)
        if (gs >= 1 && gs <= 32) blendWrite((cs + 3) & 3);
        if (cs == 0 && t9 <= 7) computeState(t9 + 1);
        if (gs <= 31) {
            if (cs == 3 && t9 <= 6)
                fnext = off2[((size_t)(b * 9 + t9 + 2) << 12) + pos0 + brow];
            gatherRegion(cs);                    // G(gs): stays in flight across next barrier
        }
        __builtin_amdgcn_sched_barrier(0);       // loads issued before MFMA

#pragma unroll
        for (int jj = 0; jj < 2; ++jj) {
            int bchunk = (cs * 8 + jj * 4 + q) << 3;
            short8 bfr[2];
            bfr[0] = *(const short8*)&BSF[(wc * 32 + m) * 264 + bchunk];
            bfr[1] = *(const short8*)&BSF[(wc * 32 + 16 + m) * 264 + bchunk];
            __builtin_amdgcn_s_setprio(1);
#pragma unroll
            for (int ao = 0; ao < 4; ++ao) {
                acc[ao][0] = __builtin_amdgcn_mfma_f32_16x16x32_bf16(af[jj * 4 + ao], bfr[0], acc[ao][0], 0, 0, 0);
                acc[ao][1] = __builtin_amdgcn_mfma_f32_16x16x32_bf16(af[jj * 4 + ao], bfr[1], acc[ao][1], 0, 0, 0);
            }
            __builtin_amdgcn_s_setprio(0);
        }
        asm volatile("s_waitcnt lgkmcnt(0)" ::: "memory");  // ds reads+writes done before next barrier
    }

    // epilogue: bias + sigmoid -> fp32 NCHW
    int nn = lane & 15;
#pragma unroll
    for (int ao = 0; ao < 4; ++ao) {
        int ob = wr * 64 + ao * 16 + q * 4;
#pragma unroll
        for (int bn = 0; bn < 2; ++bn) {
            int pos = pos0 + wc * 32 + bn * 16 + nn;
#pragma unroll
            for (int r = 0; r < 4; ++r) {
                float v = acc[ao][bn][r] + bias[ob + r];
                float sg = 1.0f / (1.0f + __expf(-v));
                out[(size_t)((b * CCH + ob + r) * NPOS) + pos] = sg;
            }
        }
    }
}

extern "C" void kernel_launch(void* const* d_in, const int* in_sizes, int n_in,
                              void* d_out, int out_size, void* d_ws, size_t ws_size,
                              hipStream_t stream) {
    const float* x     = (const float*)d_in[0];
    const float* w_off = (const float*)d_in[1];
    const float* b_off = (const float*)d_in[2];
    const float* w     = (const float*)d_in[3];
    const float* bias  = (const float*)d_in[4];
    float* out = (float*)d_out;

    char* ws = (char*)d_ws;
    u16*    xT    = (u16*)ws;
    u16*    W2r   = (u16*)(ws + W2R_OFF);
    u16*    Woff2 = (u16*)(ws + WOFF2_OFF);
    float2* off2  = (float2*)(ws + OFF2_OFF);

    if (ws_size < WS_MIN) return;

    k_pre<<<2825, 256, 0, stream>>>(w, w_off, x, W2r, Woff2, xT);
    k_off2<<<dim3(8, 32), 256, 0, stream>>>(xT, Woff2, b_off, off2);
    k_gemm<<<dim3(8, 1, 64), 512, 0, stream>>>(xT, off2, W2r, bias, out);
}